// Round 3
// baseline (409.713 us; speedup 1.0000x reference)
//
#include <hip/hip_runtime.h>

// ALSH conv setup: hash kernels, vote via 1-channel conv, histogram, argmax,
// gather active kernel set.
#define O_CH   256      // out_channels
#define C_CH   64       // in_channels
#define FLATK  576      // C*K*K
#define M_TERMS 9
#define AL     585      // D*K*K = (C + 1)*9
#define TSZ    8192     // table size
#define RADIUS 4.0f
#define NB     16
#define HH     256
#define WW     256

// workspace layout (ints):
//   [0, 256)            k_idx : bucket of each kernel
//   [256, 256+8192)     hist  : vote histogram
//   [8448]              best  : argmax bucket
//   [8449, 8449+512)    rows  : active kernel ids (-1 = empty slot)
#define WS_KIDX 0
#define WS_HIST 256
#define WS_BEST (256 + TSZ)
#define WS_ROWS (256 + TSZ + 1)

// ---------------- K1: hash kernels (1 wave per kernel) + zero histogram ----
__global__ __launch_bounds__(256) void k_init(const float* __restrict__ kernels,
                                              const float* __restrict__ a,
                                              const float* __restrict__ b,
                                              int* __restrict__ ws) {
    if (blockIdx.x < 64) {
        const int wv = threadIdx.x >> 6, lane = threadIdx.x & 63;
        const int o = blockIdx.x * 4 + wv;
        const float* wp = kernels + o * FLATK;
        float dot = 0.f, n2 = 0.f;
        #pragma unroll
        for (int j0 = 0; j0 < FLATK; j0 += 64) {   // 576/64 = 9 coalesced rounds
            float x = wp[j0 + lane];
            dot += x * a[j0 + lane];
            n2  += x * x;
        }
        #pragma unroll
        for (int off = 32; off > 0; off >>= 1) {
            dot += __shfl_xor(dot, off);
            n2  += __shfl_xor(n2, off);
        }
        if (lane == 0) {
            float p = n2, d = dot;
            for (int i = 0; i < M_TERMS; ++i) { d += p * a[FLATK + i]; p *= n2; }
            float hk = floorf((d + b[0]) / RADIUS);
            ws[WS_KIDX + o] = (int)fabsf(fmodf(hk, (float)TSZ));
        }
    } else {
        int t = (blockIdx.x - 64) * 256 + threadIdx.x;
        ws[WS_HIST + t] = 0;
    }
}

// ---------------- K2: vote conv, register-tiled, prefetched, shuffle halo --
// Block: 256 threads -> tile 256 wide x 8 tall. Thread: 4 px wide x 2 rows.
// Each wave's 64 lanes span the full 256-px row -> halo cols via shfl.
#define TILE_H 8
__global__ __launch_bounds__(256) void k_vote(const float* __restrict__ input,
                                              const float* __restrict__ a,
                                              const float* __restrict__ b,
                                              int* __restrict__ ws) {
    __shared__ int   hist_s[TSZ];   // 32 KB
    __shared__ float a_s[AL];
    const int tid = threadIdx.x;

    for (int i = tid; i < TSZ; i += 256) hist_s[i] = 0;
    for (int i = tid; i < AL; i += 256) a_s[i] = a[i];
    __syncthreads();

    const float bv = b[0];
    const int by = blockIdx.x & 31;        // 32 row-tiles per image
    const int n  = blockIdx.x >> 5;        // 16 images
    const int y0 = by * TILE_H;
    const int lane = tid & 63;             // = x-group; wave spans full row
    const int yg = tid >> 6;               // 4 waves = 4 row-pairs
    const int x4 = lane * 4;               // columns x4..x4+3
    const int ybase = y0 + yg * 2;         // rows ybase, ybase+1

    float acc[2][4] = {{0.f,0.f,0.f,0.f},{0.f,0.f,0.f,0.f}};
    const float* imgbase = input + (size_t)n * C_CH * HH * WW;

    float4 vbuf[2][4];
    // prologue: load channel 0 (rows ybase-1 .. ybase+2; bounds wave-uniform)
    #pragma unroll
    for (int r = 0; r < 4; ++r) {
        int gy = ybase - 1 + r;
        vbuf[0][r] = (gy >= 0 && gy < HH)
                   ? *(const float4*)(imgbase + gy * WW + x4)
                   : make_float4(0.f, 0.f, 0.f, 0.f);
    }

    #pragma unroll 2
    for (int c = 0; c < C_CH; ++c) {
        const int cur = c & 1, nxt = cur ^ 1;
        if (c + 1 < C_CH) {                // prefetch next channel's rows
            const float* src = imgbase + (size_t)(c + 1) * (HH * WW);
            #pragma unroll
            for (int r = 0; r < 4; ++r) {
                int gy = ybase - 1 + r;
                vbuf[nxt][r] = (gy >= 0 && gy < HH)
                             ? *(const float4*)(src + gy * WW + x4)
                             : make_float4(0.f, 0.f, 0.f, 0.f);
            }
        }
        // build 6-wide windows; halo columns from neighbor lanes (bit-exact)
        float win[4][6];
        #pragma unroll
        for (int r = 0; r < 4; ++r) {
            float4 v = vbuf[cur][r];
            float lv = __shfl_up(v.w, 1);   if (lane == 0)  lv = 0.f;
            float rv = __shfl_down(v.x, 1); if (lane == 63) rv = 0.f;
            win[r][0] = lv; win[r][1] = v.x; win[r][2] = v.y;
            win[r][3] = v.z; win[r][4] = v.w; win[r][5] = rv;
        }
        const float* ac = a_s + c * 9;
        #pragma unroll
        for (int rr = 0; rr < 2; ++rr)
            #pragma unroll
            for (int ky = 0; ky < 3; ++ky)
                #pragma unroll
                for (int p = 0; p < 4; ++p)
                    #pragma unroll
                    for (int kx = 0; kx < 3; ++kx)
                        acc[rr][p] += win[rr + ky][p + kx] * ac[ky * 3 + kx];
    }

    // constant Q-channel (0.5 inside image, zero-padded) + vote
    #pragma unroll
    for (int rr = 0; rr < 2; ++rr) {
        int gy = ybase + rr;
        #pragma unroll
        for (int p = 0; p < 4; ++p) {
            int gx = x4 + p;
            float cs = 0.f;
            #pragma unroll
            for (int ky = 0; ky < 3; ++ky) {
                int yy = gy + ky - 1;
                if (yy < 0 || yy >= HH) continue;
                #pragma unroll
                for (int kx = 0; kx < 3; ++kx) {
                    int xx = gx + kx - 1;
                    if (xx < 0 || xx >= WW) continue;
                    cs += a_s[FLATK + ky * 3 + kx];
                }
            }
            float t = acc[rr][p] + 0.5f * cs;
            float v = floorf((t + bv) / RADIUS);
            int vi = (int)fabsf(fmodf(v, (float)TSZ));
            atomicAdd(&hist_s[vi], 1);
        }
    }

    __syncthreads();
    int* hist_g = ws + WS_HIST;
    for (int i = tid; i < TSZ; i += 256) {
        int v = hist_s[i];
        if (v) atomicAdd(&hist_g[i], v);
    }
}

// ---------------- K3: argmax + count output + active row list (parallel) ---
__global__ __launch_bounds__(256) void k_finalize(int* __restrict__ ws,
                                                  float* __restrict__ out) {
    __shared__ int sv[256], si[256];
    __shared__ int wsum[4];
    const int tid = threadIdx.x;
    const int* hist = ws + WS_HIST;

    int best = -1, bidx = 0;
    for (int t = tid; t < TSZ; t += 256) {
        int v = hist[t];
        if (v > best) { best = v; bidx = t; }  // strict > keeps first occurrence
    }
    sv[tid] = best; si[tid] = bidx;
    __syncthreads();
    for (int s = 128; s > 0; s >>= 1) {
        if (tid < s) {
            if (sv[tid + s] > sv[tid] ||
                (sv[tid + s] == sv[tid] && si[tid + s] < si[tid])) {
                sv[tid] = sv[tid + s]; si[tid] = si[tid + s];
            }
        }
        __syncthreads();
    }
    const int bestIdx = si[0];

    // count (float) + index, coalesced
    float* count_out = out + 512 * FLATK;
    for (int t = tid; t < TSZ; t += 256) count_out[t] = (float)hist[t];
    if (tid == 0) {
        out[512 * FLATK + TSZ] = (float)bestIdx;
        ws[WS_BEST] = bestIdx;
    }

    // active rows via ballot prefix-scan (insertion order = ascending id)
    int* rows = ws + WS_ROWS;
    for (int i = tid; i < 2 * O_CH; i += 256) rows[i] = -1;
    const int o = tid;
    const int match = (ws[WS_KIDX + o] == bestIdx) ? 1 : 0;
    unsigned long long m = __ballot(match);
    const int lane = tid & 63, wv = tid >> 6;
    if (lane == 0) wsum[wv] = __popcll(m);
    __syncthreads();   // also orders the -1 fill before the scatter
    int prefix = 0;
    for (int i = 0; i < wv; ++i) prefix += wsum[i];
    int before = __popcll(m & ((1ull << lane) - 1ull));
    if (match) rows[prefix + before] = o;
}

// ---------------- K4: gather active kernels ----------------
__global__ void k_gather(const float* __restrict__ kernels,
                         const int* __restrict__ ws,
                         float* __restrict__ out) {
    int gid = blockIdx.x * blockDim.x + threadIdx.x;
    if (gid >= 2 * O_CH * FLATK) return;
    int s = gid / FLATK;
    int j = gid - s * FLATK;
    int r = ws[WS_ROWS + s];
    out[gid] = (r >= 0) ? kernels[r * FLATK + j] : 0.0f;
}

extern "C" void kernel_launch(void* const* d_in, const int* in_sizes, int n_in,
                              void* d_out, int out_size, void* d_ws, size_t ws_size,
                              hipStream_t stream) {
    const float* input   = (const float*)d_in[0];
    const float* kernels = (const float*)d_in[1];
    const float* a       = (const float*)d_in[2];
    const float* b       = (const float*)d_in[3];
    float* out = (float*)d_out;
    int*   ws  = (int*)d_ws;

    k_init<<<96, 256, 0, stream>>>(kernels, a, b, ws);
    k_vote<<<NB * (HH / TILE_H), 256, 0, stream>>>(input, a, b, ws);
    k_finalize<<<1, 256, 0, stream>>>(ws, out);
    k_gather<<<(2 * O_CH * FLATK + 255) / 256, 256, 0, stream>>>(kernels, ws, out);
}

// Round 4
// 406.624 us; speedup vs baseline: 1.0076x; 1.0076x over previous
//
#include <hip/hip_runtime.h>

// ALSH conv setup: hash kernels, vote via 1-channel conv, histogram, argmax,
// gather active kernel set.
#define O_CH   256      // out_channels
#define C_CH   64       // in_channels
#define FLATK  576      // C*K*K
#define M_TERMS 9
#define AL     585      // D*K*K = (C + 1)*9
#define TSZ    8192     // table size
#define RADIUS 4.0f
#define NB     16
#define HH     256
#define WW     256
#define CG     4        // channel groups
#define CPG    (C_CH / CG)   // 16 channels per group

// workspace layout (ints / floats):
//   [0, 256)            k_idx : bucket of each kernel
//   [256, 256+8192)     hist  : vote histogram
//   [8448]              best  : argmax bucket
//   [8449, 8449+512)    rows  : active kernel ids (-1 = empty slot)
//   [32768, ...)        pscratch : CG x NB x HH x WW partial conv sums (16 MB)
#define WS_KIDX 0
#define WS_HIST 256
#define WS_BEST (256 + TSZ)
#define WS_ROWS (256 + TSZ + 1)
#define WS_SCRATCH_F 32768

// ---------------- K1: hash kernels (1 wave per kernel) + zero histogram ----
__global__ __launch_bounds__(256) void k_init(const float* __restrict__ kernels,
                                              const float* __restrict__ a,
                                              const float* __restrict__ b,
                                              int* __restrict__ ws) {
    if (blockIdx.x < 64) {
        const int wv = threadIdx.x >> 6, lane = threadIdx.x & 63;
        const int o = blockIdx.x * 4 + wv;
        const float* wp = kernels + o * FLATK;
        float dot = 0.f, n2 = 0.f;
        #pragma unroll
        for (int j0 = 0; j0 < FLATK; j0 += 64) {   // 576/64 = 9 coalesced rounds
            float x = wp[j0 + lane];
            dot += x * a[j0 + lane];
            n2  += x * x;
        }
        #pragma unroll
        for (int off = 32; off > 0; off >>= 1) {
            dot += __shfl_xor(dot, off);
            n2  += __shfl_xor(n2, off);
        }
        if (lane == 0) {
            float p = n2, d = dot;
            for (int i = 0; i < M_TERMS; ++i) { d += p * a[FLATK + i]; p *= n2; }
            float hk = floorf((d + b[0]) / RADIUS);
            ws[WS_KIDX + o] = (int)fabsf(fmodf(hk, (float)TSZ));
        }
    } else {
        int t = (blockIdx.x - 64) * 256 + threadIdx.x;
        ws[WS_HIST + t] = 0;
    }
}

// ---------------- K2a: partial conv, channel-split for occupancy ----------
// Block: 256 threads -> tile 256 wide x 8 tall, 16 channels. Thread: 4px x 2rows.
// grid = 2048: bid = (n*32 + by)*CG + g
#define TILE_H 8
__global__ __launch_bounds__(256) void k_conv_part(const float* __restrict__ input,
                                                   const float* __restrict__ a,
                                                   float* __restrict__ ps) {
    __shared__ float a_s[C_CH * 9];
    const int tid = threadIdx.x;
    for (int i = tid; i < C_CH * 9; i += 256) a_s[i] = a[i];
    __syncthreads();

    const int g  = blockIdx.x & (CG - 1);
    const int t2 = blockIdx.x >> 2;
    const int by = t2 & 31;
    const int n  = t2 >> 5;
    const int y0 = by * TILE_H;
    const int lane = tid & 63;             // wave spans full 256-px row
    const int yg = tid >> 6;
    const int x4 = lane * 4;
    const int ybase = y0 + yg * 2;
    const int c0 = g * CPG;

    float acc[2][4] = {{0.f,0.f,0.f,0.f},{0.f,0.f,0.f,0.f}};
    const float* imgbase = input + (size_t)n * C_CH * HH * WW;

    float4 vbuf[2][4];
    #pragma unroll
    for (int r = 0; r < 4; ++r) {
        int gy = ybase - 1 + r;
        vbuf[0][r] = (gy >= 0 && gy < HH)
                   ? *(const float4*)(imgbase + (size_t)c0 * (HH * WW) + gy * WW + x4)
                   : make_float4(0.f, 0.f, 0.f, 0.f);
    }

    #pragma unroll 2
    for (int cc = 0; cc < CPG; ++cc) {
        const int c = c0 + cc;
        const int cur = cc & 1, nxt = cur ^ 1;
        if (cc + 1 < CPG) {                // prefetch next channel's rows
            const float* src = imgbase + (size_t)(c + 1) * (HH * WW);
            #pragma unroll
            for (int r = 0; r < 4; ++r) {
                int gy = ybase - 1 + r;
                vbuf[nxt][r] = (gy >= 0 && gy < HH)
                             ? *(const float4*)(src + gy * WW + x4)
                             : make_float4(0.f, 0.f, 0.f, 0.f);
            }
        }
        float win[4][6];
        #pragma unroll
        for (int r = 0; r < 4; ++r) {
            float4 v = vbuf[cur][r];
            float lv = __shfl_up(v.w, 1);   if (lane == 0)  lv = 0.f;
            float rv = __shfl_down(v.x, 1); if (lane == 63) rv = 0.f;
            win[r][0] = lv; win[r][1] = v.x; win[r][2] = v.y;
            win[r][3] = v.z; win[r][4] = v.w; win[r][5] = rv;
        }
        const float* ac = a_s + c * 9;
        #pragma unroll
        for (int rr = 0; rr < 2; ++rr)
            #pragma unroll
            for (int ky = 0; ky < 3; ++ky)
                #pragma unroll
                for (int p = 0; p < 4; ++p)
                    #pragma unroll
                    for (int kx = 0; kx < 3; ++kx)
                        acc[rr][p] += win[rr + ky][p + kx] * ac[ky * 3 + kx];
    }

    float* dst = ps + ((size_t)(g * NB + n) * HH) * WW;
    #pragma unroll
    for (int rr = 0; rr < 2; ++rr)
        *(float4*)(dst + (ybase + rr) * WW + x4) =
            make_float4(acc[rr][0], acc[rr][1], acc[rr][2], acc[rr][3]);
}

// ---------------- K2b: combine partials + Q-channel + vote histogram ------
__global__ __launch_bounds__(256) void k_vote2(const float* __restrict__ ps,
                                               const float* __restrict__ a,
                                               const float* __restrict__ b,
                                               int* __restrict__ ws) {
    __shared__ int hist_s[TSZ];   // 32 KB
    __shared__ float aq_s[9];
    const int tid = threadIdx.x;
    for (int i = tid; i < TSZ; i += 256) hist_s[i] = 0;
    if (tid < 9) aq_s[tid] = a[FLATK + tid];
    __syncthreads();

    const float bv = b[0];
    const int by = blockIdx.x & 31;
    const int n  = blockIdx.x >> 5;
    const int y0 = by * TILE_H;
    const int lane = tid & 63;
    const int yg = tid >> 6;
    const int x4 = lane * 4;
    const int ybase = y0 + yg * 2;

    #pragma unroll
    for (int rr = 0; rr < 2; ++rr) {
        const int gy = ybase + rr;
        float4 s = make_float4(0.f, 0.f, 0.f, 0.f);
        #pragma unroll
        for (int g = 0; g < CG; ++g) {     // ascending group = ascending c
            float4 v = *(const float4*)(ps + ((size_t)(g * NB + n) * HH + gy) * WW + x4);
            s.x += v.x; s.y += v.y; s.z += v.z; s.w += v.w;
        }
        float accv[4] = {s.x, s.y, s.z, s.w};
        #pragma unroll
        for (int p = 0; p < 4; ++p) {
            int gx = x4 + p;
            float cs = 0.f;
            #pragma unroll
            for (int ky = 0; ky < 3; ++ky) {
                int yy = gy + ky - 1;
                if (yy < 0 || yy >= HH) continue;
                #pragma unroll
                for (int kx = 0; kx < 3; ++kx) {
                    int xx = gx + kx - 1;
                    if (xx < 0 || xx >= WW) continue;
                    cs += aq_s[ky * 3 + kx];
                }
            }
            float t = accv[p] + 0.5f * cs;
            float v = floorf((t + bv) / RADIUS);
            int vi = (int)fabsf(fmodf(v, (float)TSZ));
            atomicAdd(&hist_s[vi], 1);
        }
    }

    __syncthreads();
    int* hist_g = ws + WS_HIST;
    for (int i = tid; i < TSZ; i += 256) {
        int v = hist_s[i];
        if (v) atomicAdd(&hist_g[i], v);
    }
}

// ---------------- K3: argmax + count output + active row list (parallel) ---
__global__ __launch_bounds__(256) void k_finalize(int* __restrict__ ws,
                                                  float* __restrict__ out) {
    __shared__ int sv[256], si[256];
    __shared__ int wsum[4];
    const int tid = threadIdx.x;
    const int* hist = ws + WS_HIST;

    int best = -1, bidx = 0;
    for (int t = tid; t < TSZ; t += 256) {
        int v = hist[t];
        if (v > best) { best = v; bidx = t; }  // strict > keeps first occurrence
    }
    sv[tid] = best; si[tid] = bidx;
    __syncthreads();
    for (int s = 128; s > 0; s >>= 1) {
        if (tid < s) {
            if (sv[tid + s] > sv[tid] ||
                (sv[tid + s] == sv[tid] && si[tid + s] < si[tid])) {
                sv[tid] = sv[tid + s]; si[tid] = si[tid + s];
            }
        }
        __syncthreads();
    }
    const int bestIdx = si[0];

    float* count_out = out + 512 * FLATK;
    for (int t = tid; t < TSZ; t += 256) count_out[t] = (float)hist[t];
    if (tid == 0) {
        out[512 * FLATK + TSZ] = (float)bestIdx;
        ws[WS_BEST] = bestIdx;
    }

    // active rows via ballot prefix-scan (insertion order = ascending id)
    int* rows = ws + WS_ROWS;
    for (int i = tid; i < 2 * O_CH; i += 256) rows[i] = -1;
    const int o = tid;
    const int match = (ws[WS_KIDX + o] == bestIdx) ? 1 : 0;
    unsigned long long m = __ballot(match);
    const int lane = tid & 63, wv = tid >> 6;
    if (lane == 0) wsum[wv] = __popcll(m);
    __syncthreads();   // also orders the -1 fill before the scatter
    int prefix = 0;
    for (int i = 0; i < wv; ++i) prefix += wsum[i];
    int before = __popcll(m & ((1ull << lane) - 1ull));
    if (match) rows[prefix + before] = o;
}

// ---------------- K4: gather active kernels ----------------
__global__ void k_gather(const float* __restrict__ kernels,
                         const int* __restrict__ ws,
                         float* __restrict__ out) {
    int gid = blockIdx.x * blockDim.x + threadIdx.x;
    if (gid >= 2 * O_CH * FLATK) return;
    int s = gid / FLATK;
    int j = gid - s * FLATK;
    int r = ws[WS_ROWS + s];
    out[gid] = (r >= 0) ? kernels[r * FLATK + j] : 0.0f;
}

extern "C" void kernel_launch(void* const* d_in, const int* in_sizes, int n_in,
                              void* d_out, int out_size, void* d_ws, size_t ws_size,
                              hipStream_t stream) {
    const float* input   = (const float*)d_in[0];
    const float* kernels = (const float*)d_in[1];
    const float* a       = (const float*)d_in[2];
    const float* b       = (const float*)d_in[3];
    float* out = (float*)d_out;
    int*   ws  = (int*)d_ws;
    float* ps  = (float*)d_ws + WS_SCRATCH_F;

    k_init<<<96, 256, 0, stream>>>(kernels, a, b, ws);
    k_conv_part<<<NB * (HH / TILE_H) * CG, 256, 0, stream>>>(input, a, ps);
    k_vote2<<<NB * (HH / TILE_H), 256, 0, stream>>>(ps, a, b, ws);
    k_finalize<<<1, 256, 0, stream>>>(ws, out);
    k_gather<<<(2 * O_CH * FLATK + 255) / 256, 256, 0, stream>>>(kernels, ws, out);
}

// Round 5
// 405.749 us; speedup vs baseline: 1.0098x; 1.0022x over previous
//
#include <hip/hip_runtime.h>

// ALSH conv setup: hash kernels, vote via 1-channel conv, histogram, argmax,
// gather active kernel set.
#define O_CH   256      // out_channels
#define C_CH   64       // in_channels
#define FLATK  576      // C*K*K
#define M_TERMS 9
#define AL     585      // D*K*K = (C + 1)*9
#define TSZ    8192     // table size
#define RADIUS 4.0f
#define NB     16
#define HH     256
#define WW     256

// workspace layout (ints):
//   [0, 256)            k_idx : bucket of each kernel
//   [256, 256+8192)     hist  : vote histogram
//   [8448]              best  : argmax bucket
//   [8449, 8449+512)    rows  : active kernel ids (-1 = empty slot)
#define WS_KIDX 0
#define WS_HIST 256
#define WS_BEST (256 + TSZ)
#define WS_ROWS (256 + TSZ + 1)

// ---------------- K1: hash kernels (1 wave per kernel) + zero histogram ----
__global__ __launch_bounds__(256) void k_init(const float* __restrict__ kernels,
                                              const float* __restrict__ a,
                                              const float* __restrict__ b,
                                              int* __restrict__ ws) {
    if (blockIdx.x < 64) {
        const int wv = threadIdx.x >> 6, lane = threadIdx.x & 63;
        const int o = blockIdx.x * 4 + wv;
        const float* wp = kernels + o * FLATK;
        float dot = 0.f, n2 = 0.f;
        #pragma unroll
        for (int j0 = 0; j0 < FLATK; j0 += 64) {   // 576/64 = 9 coalesced rounds
            float x = wp[j0 + lane];
            dot += x * a[j0 + lane];
            n2  += x * x;
        }
        #pragma unroll
        for (int off = 32; off > 0; off >>= 1) {
            dot += __shfl_xor(dot, off);
            n2  += __shfl_xor(n2, off);
        }
        if (lane == 0) {
            float p = n2, d = dot;
            for (int i = 0; i < M_TERMS; ++i) { d += p * a[FLATK + i]; p *= n2; }
            float hk = floorf((d + b[0]) / RADIUS);
            ws[WS_KIDX + o] = (int)fabsf(fmodf(hk, (float)TSZ));
        }
    } else {
        int t = (blockIdx.x - 64) * 256 + threadIdx.x;
        ws[WS_HIST + t] = 0;
    }
}

// ---------------- K2: fused vote conv, TILE_H=16, 512 threads -------------
// Block: 512 threads -> tile 256 wide x 16 tall. Thread: 4 px x 2 rows.
// Wave spans the full 256-px row -> halo columns via shfl (bit-exact).
// Grid 256 blocks; XCD-contiguous tile swizzle so vertical halo rows hit
// the per-XCD L2.
#define TILE_H 16
__global__ __launch_bounds__(512) void k_vote(const float* __restrict__ input,
                                              const float* __restrict__ a,
                                              const float* __restrict__ b,
                                              int* __restrict__ ws) {
    __shared__ int   hist_s[TSZ];   // 32 KB
    __shared__ float a_s[AL];
    const int tid = threadIdx.x;

    for (int i = tid; i < TSZ; i += 512) hist_s[i] = 0;
    for (int i = tid; i < AL; i += 512) a_s[i] = a[i];
    __syncthreads();

    const float bv = b[0];
    // swizzle: xcd = blockIdx&7 gets 32 consecutive tiles (2 whole images)
    const int t   = (blockIdx.x & 7) * 32 + (blockIdx.x >> 3);
    const int by  = t & 15;                // 16 row-tiles per image
    const int n   = t >> 4;                // 16 images
    const int y0  = by * TILE_H;
    const int lane = tid & 63;             // wave spans full 256-px row
    const int yg  = tid >> 6;              // 8 waves = 8 row-pairs
    const int x4  = lane * 4;              // columns x4..x4+3
    const int ybase = y0 + yg * 2;         // rows ybase, ybase+1

    float acc[2][4] = {{0.f,0.f,0.f,0.f},{0.f,0.f,0.f,0.f}};
    const float* imgbase = input + (size_t)n * C_CH * HH * WW;

    float4 vbuf[2][4];
    #pragma unroll
    for (int r = 0; r < 4; ++r) {          // input rows ybase-1 .. ybase+2
        int gy = ybase - 1 + r;
        vbuf[0][r] = (gy >= 0 && gy < HH)
                   ? *(const float4*)(imgbase + gy * WW + x4)
                   : make_float4(0.f, 0.f, 0.f, 0.f);
    }

    #pragma unroll 2
    for (int c = 0; c < C_CH; ++c) {
        const int cur = c & 1, nxt = cur ^ 1;
        if (c + 1 < C_CH) {                // prefetch next channel's rows
            const float* src = imgbase + (size_t)(c + 1) * (HH * WW);
            #pragma unroll
            for (int r = 0; r < 4; ++r) {
                int gy = ybase - 1 + r;
                vbuf[nxt][r] = (gy >= 0 && gy < HH)
                             ? *(const float4*)(src + gy * WW + x4)
                             : make_float4(0.f, 0.f, 0.f, 0.f);
            }
        }
        float win[4][6];
        #pragma unroll
        for (int r = 0; r < 4; ++r) {
            float4 v = vbuf[cur][r];
            float lv = __shfl_up(v.w, 1);   if (lane == 0)  lv = 0.f;
            float rv = __shfl_down(v.x, 1); if (lane == 63) rv = 0.f;
            win[r][0] = lv; win[r][1] = v.x; win[r][2] = v.y;
            win[r][3] = v.z; win[r][4] = v.w; win[r][5] = rv;
        }
        const float* ac = a_s + c * 9;
        #pragma unroll
        for (int rr = 0; rr < 2; ++rr)
            #pragma unroll
            for (int ky = 0; ky < 3; ++ky)
                #pragma unroll
                for (int p = 0; p < 4; ++p)
                    #pragma unroll
                    for (int kx = 0; kx < 3; ++kx)
                        acc[rr][p] += win[rr + ky][p + kx] * ac[ky * 3 + kx];
    }

    // constant Q-channel (0.5 inside image, zero-padded) + vote
    #pragma unroll
    for (int rr = 0; rr < 2; ++rr) {
        int gy = ybase + rr;
        #pragma unroll
        for (int p = 0; p < 4; ++p) {
            int gx = x4 + p;
            float cs = 0.f;
            #pragma unroll
            for (int ky = 0; ky < 3; ++ky) {
                int yy = gy + ky - 1;
                if (yy < 0 || yy >= HH) continue;
                #pragma unroll
                for (int kx = 0; kx < 3; ++kx) {
                    int xx = gx + kx - 1;
                    if (xx < 0 || xx >= WW) continue;
                    cs += a_s[FLATK + ky * 3 + kx];
                }
            }
            float tt = acc[rr][p] + 0.5f * cs;
            float v = floorf((tt + bv) / RADIUS);
            int vi = (int)fabsf(fmodf(v, (float)TSZ));
            atomicAdd(&hist_s[vi], 1);
        }
    }

    __syncthreads();
    int* hist_g = ws + WS_HIST;
    for (int i = tid; i < TSZ; i += 512) {
        int v = hist_s[i];
        if (v) atomicAdd(&hist_g[i], v);
    }
}

// ---------------- K3: argmax + count output + active row list (parallel) ---
__global__ __launch_bounds__(256) void k_finalize(int* __restrict__ ws,
                                                  float* __restrict__ out) {
    __shared__ int sv[256], si[256];
    __shared__ int wsum[4];
    const int tid = threadIdx.x;
    const int* hist = ws + WS_HIST;

    int best = -1, bidx = 0;
    for (int t = tid; t < TSZ; t += 256) {
        int v = hist[t];
        if (v > best) { best = v; bidx = t; }  // strict > keeps first occurrence
    }
    sv[tid] = best; si[tid] = bidx;
    __syncthreads();
    for (int s = 128; s > 0; s >>= 1) {
        if (tid < s) {
            if (sv[tid + s] > sv[tid] ||
                (sv[tid + s] == sv[tid] && si[tid + s] < si[tid])) {
                sv[tid] = sv[tid + s]; si[tid] = si[tid + s];
            }
        }
        __syncthreads();
    }
    const int bestIdx = si[0];

    float* count_out = out + 512 * FLATK;
    for (int t = tid; t < TSZ; t += 256) count_out[t] = (float)hist[t];
    if (tid == 0) {
        out[512 * FLATK + TSZ] = (float)bestIdx;
        ws[WS_BEST] = bestIdx;
    }

    // active rows via ballot prefix-scan (insertion order = ascending id)
    int* rows = ws + WS_ROWS;
    for (int i = tid; i < 2 * O_CH; i += 256) rows[i] = -1;
    const int o = tid;
    const int match = (ws[WS_KIDX + o] == bestIdx) ? 1 : 0;
    unsigned long long m = __ballot(match);
    const int lane = tid & 63, wv = tid >> 6;
    if (lane == 0) wsum[wv] = __popcll(m);
    __syncthreads();   // also orders the -1 fill before the scatter
    int prefix = 0;
    for (int i = 0; i < wv; ++i) prefix += wsum[i];
    int before = __popcll(m & ((1ull << lane) - 1ull));
    if (match) rows[prefix + before] = o;
}

// ---------------- K4: gather active kernels ----------------
__global__ void k_gather(const float* __restrict__ kernels,
                         const int* __restrict__ ws,
                         float* __restrict__ out) {
    int gid = blockIdx.x * blockDim.x + threadIdx.x;
    if (gid >= 2 * O_CH * FLATK) return;
    int s = gid / FLATK;
    int j = gid - s * FLATK;
    int r = ws[WS_ROWS + s];
    out[gid] = (r >= 0) ? kernels[r * FLATK + j] : 0.0f;
}

extern "C" void kernel_launch(void* const* d_in, const int* in_sizes, int n_in,
                              void* d_out, int out_size, void* d_ws, size_t ws_size,
                              hipStream_t stream) {
    const float* input   = (const float*)d_in[0];
    const float* kernels = (const float*)d_in[1];
    const float* a       = (const float*)d_in[2];
    const float* b       = (const float*)d_in[3];
    float* out = (float*)d_out;
    int*   ws  = (int*)d_ws;

    k_init<<<96, 256, 0, stream>>>(kernels, a, b, ws);
    k_vote<<<NB * (HH / TILE_H), 512, 0, stream>>>(input, a, b, ws);
    k_finalize<<<1, 256, 0, stream>>>(ws, out);
    k_gather<<<(2 * O_CH * FLATK + 255) / 256, 256, 0, stream>>>(kernels, ws, out);
}